// Round 3
// baseline (2237.358 us; speedup 1.0000x reference)
//
#include <hip/hip_runtime.h>
#include <hip/hip_bf16.h>

// Problem constants (match reference)
#define B_GR   128
#define GWID   30
#define IWID   90
#define C_IN   32
#define R_REL  8
#define NBAS   4
#define N_NODES (B_GR*GWID*GWID)   // 115200
#define E_EDGES (N_NODES*8)        // 921600
#define NEG_SLOPE 0.01f

#define ELIST_CAP ((E_EDGES + R_REL*64 + 63)/64*64)   // 922112
#define NTILES (ELIST_CAP/64)                          // 14408
#define NCHUNK 256
#define CHUNK  (E_EDGES/NCHUNK)    // 3600

#define SCAN_BLOCKS (N_NODES/256)  // 450

// ======================================================================
// Weight prep: Wcat[k][r*dout+c] = sum_b comp[r,b]*bases[b,k,c]
// (concatenated-relations layout: B matrix of the dense proj GEMM)
// ======================================================================
__global__ void k_wcomp_cat(const float* __restrict__ bases, const float* __restrict__ comp,
                            float* __restrict__ Wcat, int din, int dout) {
    int idx = blockIdx.x*256 + threadIdx.x;
    int tot = R_REL*din*dout;
    if (idx >= tot) return;
    int r = idx/(din*dout), rem = idx%(din*dout);
    int k = rem/dout, c = rem%dout;
    float acc = 0.f;
    #pragma unroll
    for (int b = 0; b < NBAS; ++b)
        acc += comp[r*NBAS + b]*bases[((size_t)b*din + k)*dout + c];
    Wcat[(size_t)k*(R_REL*dout) + r*dout + c] = acc;
}

// ======================================================================
// dst-CSR build (once per call; topology reused across all 3 layers)
// ======================================================================
__global__ void k_deg(const int* __restrict__ dst, int* __restrict__ deg) {
    int e = blockIdx.x*256 + threadIdx.x;
    if (e < E_EDGES) atomicAdd(&deg[dst[e]], 1);   // avg 8-way contention: cheap
}
// block-level exclusive scan of deg -> rowptr (partial), block sums -> bsum
__global__ __launch_bounds__(256) void k_scan1(const int* __restrict__ deg,
                                               int* __restrict__ rowptr,
                                               int* __restrict__ bsum) {
    __shared__ int s[256], s2[256];
    const int tid = threadIdx.x, gid = blockIdx.x*256 + tid;
    int v = deg[gid];
    s[tid] = v;
    __syncthreads();
    int* cur = s; int* nxt = s2;
    for (int d = 1; d < 256; d <<= 1) {
        int val = cur[tid];
        if (tid >= d) val += cur[tid - d];
        nxt[tid] = val;
        __syncthreads();
        int* t = cur; cur = nxt; nxt = t;
    }
    rowptr[gid] = cur[tid] - v;
    if (tid == 255) bsum[blockIdx.x] = cur[255];
}
__global__ __launch_bounds__(512) void k_scan2(int* __restrict__ bsum, int* __restrict__ rowptr) {
    __shared__ int s[512], s2[512];
    const int tid = threadIdx.x;
    int v = (tid < SCAN_BLOCKS) ? bsum[tid] : 0;
    s[tid] = v;
    __syncthreads();
    int* cur = s; int* nxt = s2;
    for (int d = 1; d < 512; d <<= 1) {
        int val = cur[tid];
        if (tid >= d) val += cur[tid - d];
        nxt[tid] = val;
        __syncthreads();
        int* t = cur; cur = nxt; nxt = t;
    }
    if (tid < SCAN_BLOCKS) bsum[tid] = cur[tid] - v;   // exclusive
    if (tid == 0) rowptr[N_NODES] = E_EDGES;
}
__global__ void k_scan3(int* __restrict__ rowptr, const int* __restrict__ bsum,
                        int* __restrict__ cursor) {
    int gid = blockIdx.x*256 + threadIdx.x;
    int v = rowptr[gid] + bsum[blockIdx.x];
    rowptr[gid] = v;
    cursor[gid] = v;
}
__global__ void k_scatter_dst(const int* __restrict__ dst, int* __restrict__ cursor,
                              int* __restrict__ eidx) {
    int e = blockIdx.x*256 + threadIdx.x;
    if (e < E_EDGES) {
        int pos = atomicAdd(&cursor[dst[e]], 1);
        eidx[pos] = e;
    }
}
// fuse per-slot gather metadata: pidx = proj row id, pnorm = edge norm
__global__ void k_mkpairs(const int* __restrict__ eidx, const int* __restrict__ src,
                          const int* __restrict__ et, const float* __restrict__ norm,
                          int* __restrict__ pidx, float* __restrict__ pnorm) {
    int j = blockIdx.x*256 + threadIdx.x;
    if (j < E_EDGES) {
        int e = eidx[j];
        pidx[j]  = src[e]*R_REL + et[e];
        pnorm[j] = norm[e];
    }
}

// ======================================================================
// Dense proj GEMM: proj[n, r*DOUT+c] = sum_k h[n,k] * Wcat[k, r*DOUT+c]
// 64x128 tile, 256 threads, TX=32 (float4 cols) x TY=8, 8 rows/thread
// ======================================================================
template<int DIN, int DOUT>
__global__ __launch_bounds__(256) void k_projgemm(const float* __restrict__ h,
        const float* __restrict__ Wcat, float* __restrict__ proj) {
    constexpr int DCOLS = R_REL*DOUT;
    __shared__ float As[64][DIN+1];
    __shared__ float Bs[DIN][128];
    const int tid = threadIdx.x;
    const int row0 = blockIdx.x*64;
    const int col0 = blockIdx.y*128;

    for (int idx = tid; idx < 64*DIN; idx += 256) {
        int r = idx/DIN, k = idx%DIN;
        As[r][k] = h[(size_t)(row0+r)*DIN + k];
    }
    for (int idx = tid; idx < DIN*128; idx += 256) {
        int k = idx/128, j = idx%128;
        Bs[k][j] = Wcat[(size_t)k*DCOLS + col0 + j];
    }
    __syncthreads();

    const int tx = tid % 32, ty = tid / 32;
    float4 acc[8];
    #pragma unroll
    for (int i = 0; i < 8; ++i) acc[i] = make_float4(0.f,0.f,0.f,0.f);

    #pragma unroll 8
    for (int k = 0; k < DIN; ++k) {
        float4 bv = *reinterpret_cast<const float4*>(&Bs[k][tx*4]);
        #pragma unroll
        for (int i = 0; i < 8; ++i) {
            float a = As[ty*8+i][k];
            acc[i].x += a*bv.x; acc[i].y += a*bv.y;
            acc[i].z += a*bv.z; acc[i].w += a*bv.w;
        }
    }
    #pragma unroll
    for (int i = 0; i < 8; ++i) {
        *reinterpret_cast<float4*>(&proj[(size_t)(row0+ty*8+i)*DCOLS + col0 + tx*4]) = acc[i];
    }
}

// ======================================================================
// self-loop GEMM: tmp = h @ loopw + bias
// ======================================================================
template<int DIN, int DOUT>
__global__ __launch_bounds__(256) void k_selfgemm(const float* __restrict__ h,
        const float* __restrict__ loopw, const float* __restrict__ bias,
        float* __restrict__ out) {
    __shared__ float As[64][DIN+1];
    __shared__ float Bs[DIN][DOUT];
    const int tid = threadIdx.x;
    const int row0 = blockIdx.x*64;
    for (int idx = tid; idx < 64*DIN; idx += 256) {
        int r = idx/DIN, k = idx%DIN;
        As[r][k] = h[(size_t)(row0+r)*DIN + k];
    }
    for (int idx = tid; idx < DIN*DOUT; idx += 256)
        Bs[idx/DOUT][idx%DOUT] = loopw[idx];
    __syncthreads();

    constexpr int TX = DOUT/4;
    constexpr int TY = 256/TX;
    constexpr int RPT = 64/TY;
    const int tx = tid % TX, ty = tid / TX;
    float acc[RPT][4];
    #pragma unroll
    for (int i = 0; i < RPT; ++i) { acc[i][0]=acc[i][1]=acc[i][2]=acc[i][3]=0.f; }

    #pragma unroll 8
    for (int k = 0; k < DIN; ++k) {
        float4 bv = *reinterpret_cast<const float4*>(&Bs[k][tx*4]);
        #pragma unroll
        for (int i = 0; i < RPT; ++i) {
            float a = As[ty*RPT+i][k];
            acc[i][0] += a*bv.x; acc[i][1] += a*bv.y;
            acc[i][2] += a*bv.z; acc[i][3] += a*bv.w;
        }
    }
    float b0 = bias[tx*4+0], b1 = bias[tx*4+1], b2 = bias[tx*4+2], b3 = bias[tx*4+3];
    #pragma unroll
    for (int i = 0; i < RPT; ++i) {
        float* o = &out[(size_t)(row0 + ty*RPT + i)*DOUT + tx*4];
        o[0] = acc[i][0]+b0; o[1] = acc[i][1]+b1; o[2] = acc[i][2]+b2; o[3] = acc[i][3]+b3;
    }
}

// ======================================================================
// CSR gather + self + activation:  hout[n] = act(tmp[n] + sum_j pnorm*proj[pidx])
// DOUT/4 threads per node, one float4 per thread. ACT: 0=leaky, 1=sigmoid
// ======================================================================
template<int DOUT, int ACT>
__global__ __launch_bounds__(256) void k_gather(const float* __restrict__ proj,
        const float* __restrict__ tmp, const int* __restrict__ rowptr,
        const int* __restrict__ pidx, const float* __restrict__ pnorm,
        float* __restrict__ hout) {
    constexpr int TPN = DOUT/4;
    constexpr int NPB = 256/TPN;
    const int node = blockIdx.x*NPB + threadIdx.x/TPN;
    const int q = threadIdx.x % TPN;
    float4 acc = *reinterpret_cast<const float4*>(&tmp[(size_t)node*DOUT + q*4]);
    const int beg = rowptr[node], end = rowptr[node+1];
    for (int j = beg; j < end; ++j) {
        int p = pidx[j];
        float nm = pnorm[j];
        float4 v = *reinterpret_cast<const float4*>(&proj[(size_t)p*DOUT + q*4]);
        acc.x += nm*v.x; acc.y += nm*v.y; acc.z += nm*v.z; acc.w += nm*v.w;
    }
    if (ACT == 0) {
        acc.x = (acc.x >= 0.f) ? acc.x : NEG_SLOPE*acc.x;
        acc.y = (acc.y >= 0.f) ? acc.y : NEG_SLOPE*acc.y;
        acc.z = (acc.z >= 0.f) ? acc.z : NEG_SLOPE*acc.z;
        acc.w = (acc.w >= 0.f) ? acc.w : NEG_SLOPE*acc.w;
    } else {
        acc.x = 1.f/(1.f + __expf(-acc.x));
        acc.y = 1.f/(1.f + __expf(-acc.y));
        acc.z = 1.f/(1.f + __expf(-acc.z));
        acc.w = 1.f/(1.f + __expf(-acc.w));
    }
    *reinterpret_cast<float4*>(&hout[(size_t)node*DOUT + q*4]) = acc;
}

// ======================================================================
// FALLBACK path (if ws too small): round-2 etype-sort + atomic edge GEMM
// ======================================================================
__global__ __launch_bounds__(256) void k_hist(const int* __restrict__ et,
                                              int* __restrict__ hist_g) {
    __shared__ int h[R_REL][33];
    const int tid = threadIdx.x, b = blockIdx.x;
    for (int i = tid; i < R_REL*33; i += 256) ((int*)h)[i] = 0;
    __syncthreads();
    const int base = b*CHUNK;
    for (int i = tid; i < CHUNK; i += 256) {
        int r = et[base + i];
        atomicAdd(&h[r][tid & 31], 1);
    }
    __syncthreads();
    if (tid < R_REL) {
        int s = 0;
        #pragma unroll
        for (int c = 0; c < 32; ++c) s += h[tid][c];
        hist_g[tid*NCHUNK + b] = s;
    }
}
__global__ __launch_bounds__(256) void k_scan8(const int* __restrict__ hist_g,
                                               int* __restrict__ base_g,
                                               int* __restrict__ offs) {
    __shared__ int s[NCHUNK];
    __shared__ int s2[NCHUNK];
    const int tid = threadIdx.x;
    int acc = 0;
    for (int r = 0; r < R_REL; ++r) {
        int v = hist_g[r*NCHUNK + tid];
        s[tid] = v;
        __syncthreads();
        int* cur = s; int* nxt = s2;
        for (int d = 1; d < NCHUNK; d <<= 1) {
            int val = cur[tid];
            if (tid >= d) val += cur[tid - d];
            nxt[tid] = val;
            __syncthreads();
            int* t = cur; cur = nxt; nxt = t;
        }
        int incl = cur[tid];
        base_g[r*NCHUNK + tid] = acc + incl - v;
        if (tid == 0) offs[r] = acc;
        int total = cur[NCHUNK-1];
        acc += ((total + 63)/64)*64;
        __syncthreads();
    }
    if (tid == 0) offs[R_REL] = acc;
}
__global__ __launch_bounds__(256) void k_scatter2(const int* __restrict__ et,
                                                  const int* __restrict__ base_g,
                                                  int* __restrict__ elist) {
    __shared__ int cur[R_REL];
    const int tid = threadIdx.x, b = blockIdx.x;
    if (tid < R_REL) cur[tid] = base_g[tid*NCHUNK + b];
    __syncthreads();
    const int base = b*CHUNK;
    for (int i = tid; i < CHUNK; i += 256) {
        int e = base + i;
        int r = et[e];
        int pos = atomicAdd(&cur[r], 1);
        elist[pos] = e;
    }
}
template<int DIN, int DOUT>
__global__ __launch_bounds__(256) void k_edgegemm(const float* __restrict__ h,
        const float* __restrict__ Wcat, const int* __restrict__ src, const int* __restrict__ dst,
        const float* __restrict__ norm, const int* __restrict__ elist,
        const int* __restrict__ offs, float* __restrict__ agg) {
    __shared__ float As[64][DIN+1];
    __shared__ float Bs[DIN][DOUT];
    __shared__ int   s_e[64];
    __shared__ int   s_src[64];
    __shared__ int   s_dst[64];
    __shared__ float s_norm[64];
    __shared__ int   s_et;
    const int tid = threadIdx.x;
    const int pos0 = blockIdx.x*64;

    if (tid == 0) {
        int r = R_REL-1;
        #pragma unroll
        for (int i = 0; i < R_REL; ++i)
            if (pos0 >= offs[i] && pos0 < offs[i+1]) { r = i; break; }
        s_et = r;
    }
    if (tid < 64) {
        int e = elist[pos0 + tid];
        s_e[tid] = e;
        s_src[tid]  = (e >= 0) ? src[e]  : 0;
        s_dst[tid]  = (e >= 0) ? dst[e]  : 0;
        s_norm[tid] = (e >= 0) ? norm[e] : 0.f;
    }
    __syncthreads();

    for (int idx = tid; idx < 64*DIN; idx += 256) {
        int r = idx/DIN, k = idx%DIN;
        As[r][k] = h[(size_t)s_src[r]*DIN + k] * s_norm[r];
    }
    for (int idx = tid; idx < DIN*DOUT; idx += 256) {
        int k = idx/DOUT, c = idx%DOUT;
        Bs[k][c] = Wcat[(size_t)k*(R_REL*DOUT) + s_et*DOUT + c];
    }
    __syncthreads();

    constexpr int TX = DOUT/4;
    constexpr int TY = 256/TX;
    constexpr int RPT = 64/TY;
    const int tx = tid % TX, ty = tid / TX;
    float acc[RPT][4];
    #pragma unroll
    for (int i = 0; i < RPT; ++i) { acc[i][0]=acc[i][1]=acc[i][2]=acc[i][3]=0.f; }

    #pragma unroll 8
    for (int k = 0; k < DIN; ++k) {
        float4 bv = *reinterpret_cast<const float4*>(&Bs[k][tx*4]);
        #pragma unroll
        for (int i = 0; i < RPT; ++i) {
            float a = As[ty*RPT+i][k];
            acc[i][0] += a*bv.x; acc[i][1] += a*bv.y;
            acc[i][2] += a*bv.z; acc[i][3] += a*bv.w;
        }
    }
    #pragma unroll
    for (int i = 0; i < RPT; ++i) {
        int r = ty*RPT + i;
        if (s_e[r] >= 0) {
            float* o = &agg[(size_t)s_dst[r]*DOUT + tx*4];
            atomicAdd(o+0, acc[i][0]); atomicAdd(o+1, acc[i][1]);
            atomicAdd(o+2, acc[i][2]); atomicAdd(o+3, acc[i][3]);
        }
    }
}
__global__ void k_leaky(float* __restrict__ x, int n) {
    int i = blockIdx.x*256 + threadIdx.x;
    if (i < n) { float v = x[i]; x[i] = (v >= 0.f) ? v : NEG_SLOPE*v; }
}
__global__ void k_sigmoid(float* __restrict__ x, int n) {
    int i = blockIdx.x*256 + threadIdx.x;
    if (i < n) { float v = x[i]; x[i] = 1.f/(1.f + __expf(-v)); }
}

// ======================================================================
// conv-transpose decoder + sigmoid
// ======================================================================
__global__ __launch_bounds__(256) void k_convt(const float* __restrict__ logits,
        const float* __restrict__ w, const float* __restrict__ cb, float* __restrict__ out) {
    __shared__ float s_w[49*32];
    const int tid = threadIdx.x;
    for (int idx = tid; idx < 49*32; idx += 256) {
        int tap = idx/32, c = idx%32;
        s_w[tap*32 + c] = w[c*49 + tap];
    }
    __syncthreads();
    int g = blockIdx.x*256 + tid;
    if (g >= B_GR*IWID*IWID) return;
    int b = g/(IWID*IWID);
    int rem = g%(IWID*IWID);
    int oy = rem/IWID, ox = rem%IWID;

    float acc = cb[0];
    for (int ky = 0; ky < 7; ++ky) {
        int t = oy + 2 - ky;
        if (t < 0 || (t % 3) != 0) continue;
        int iy = t/3; if (iy >= GWID) continue;
        for (int kx = 0; kx < 7; ++kx) {
            int u = ox + 2 - kx;
            if (u < 0 || (u % 3) != 0) continue;
            int ix = u/3; if (ix >= GWID) continue;
            const float4* xp = reinterpret_cast<const float4*>(&logits[(((size_t)b*GWID + iy)*GWID + ix)*32]);
            const float4* wp = reinterpret_cast<const float4*>(&s_w[(ky*7 + kx)*32]);
            #pragma unroll
            for (int c4 = 0; c4 < 8; ++c4) {
                float4 xv = xp[c4], wv = wp[c4];
                acc += xv.x*wv.x + xv.y*wv.y + xv.z*wv.z + xv.w*wv.w;
            }
        }
    }
    out[g] = 1.f/(1.f + __expf(-acc));
}

// ======================================================================
// host
// ======================================================================
extern "C" void kernel_launch(void* const* d_in, const int* in_sizes, int n_in,
                              void* d_out, int out_size, void* d_ws, size_t ws_size,
                              hipStream_t stream) {
    const float* features = (const float*)d_in[0];
    const int*   src      = (const int*)  d_in[1];
    const int*   dst      = (const int*)  d_in[2];
    const int*   etypes   = (const int*)  d_in[3];
    const float* norm     = (const float*)d_in[4];
    const float* bases0 = (const float*)d_in[5];
    const float* comp0  = (const float*)d_in[6];
    const float* loop0  = (const float*)d_in[7];
    const float* bias0  = (const float*)d_in[8];
    const float* bases1 = (const float*)d_in[9];
    const float* comp1  = (const float*)d_in[10];
    const float* loop1  = (const float*)d_in[11];
    const float* bias1  = (const float*)d_in[12];
    const float* bases2 = (const float*)d_in[13];
    const float* comp2  = (const float*)d_in[14];
    const float* loop2  = (const float*)d_in[15];
    const float* bias2  = (const float*)d_in[16];
    const float* conv_w = (const float*)d_in[17];
    const float* conv_b = (const float*)d_in[18];
    float* out = (float*)d_out;

    // ---- common workspace carve-up (float units) ----
    float* ws = (float*)d_ws;
    size_t off = 0;
    float* Wcat0 = ws + off; off += (size_t)R_REL*32*64;   // 16384
    float* Wcat1 = ws + off; off += (size_t)R_REL*64*64;   // 32768
    float* Wcat2 = ws + off; off += (size_t)R_REL*64*32;   // 16384
    float* h1     = ws + off; off += (size_t)N_NODES*64;
    float* h2     = ws + off; off += (size_t)N_NODES*64;
    float* logits = ws + off; off += (size_t)N_NODES*32;
    size_t branch_off = off;

    // main-path buffers
    float* tmp    = ws + off; off += (size_t)N_NODES*64;
    int*   rowptr = (int*)(ws + off); off += (size_t)N_NODES + 4;
    int*   deg    = (int*)(ws + off); off += (size_t)N_NODES;      // also cursor
    int*   eidx   = (int*)(ws + off); off += (size_t)E_EDGES;
    int*   pidx   = (int*)(ws + off); off += (size_t)E_EDGES;
    float* pnorm  = ws + off; off += (size_t)E_EDGES;
    int*   bsum   = (int*)(ws + off); off += 512;
    off = (off + 3) & ~(size_t)3;
    float* proj   = ws + off; off += (size_t)N_NODES*R_REL*64;     // 236 MB
    size_t needed_main = off * sizeof(float);

    const int NROWT = N_NODES/64;   // 1800
    const int ebl = (E_EDGES + 255)/256;

    // weight prep (both paths)
    k_wcomp_cat<<<(R_REL*32*64 + 255)/256, 256, 0, stream>>>(bases0, comp0, Wcat0, 32, 64);
    k_wcomp_cat<<<(R_REL*64*64 + 255)/256, 256, 0, stream>>>(bases1, comp1, Wcat1, 64, 64);
    k_wcomp_cat<<<(R_REL*64*32 + 255)/256, 256, 0, stream>>>(bases2, comp2, Wcat2, 64, 32);

    if (ws_size >= needed_main) {
        // ================= main path: dense proj + CSR gather =================
        hipMemsetAsync(deg, 0, (size_t)N_NODES*sizeof(int), stream);
        k_deg        <<<ebl, 256, 0, stream>>>(dst, deg);
        k_scan1      <<<SCAN_BLOCKS, 256, 0, stream>>>(deg, rowptr, bsum);
        k_scan2      <<<1, 512, 0, stream>>>(bsum, rowptr);
        k_scan3      <<<SCAN_BLOCKS, 256, 0, stream>>>(rowptr, bsum, deg);  // deg becomes cursor
        k_scatter_dst<<<ebl, 256, 0, stream>>>(dst, deg, eidx);
        k_mkpairs    <<<ebl, 256, 0, stream>>>(eidx, src, etypes, norm, pidx, pnorm);

        // layer 0: 32 -> 64, leaky
        k_selfgemm<32,64><<<NROWT, 256, 0, stream>>>(features, loop0, bias0, tmp);
        k_projgemm<32,64><<<dim3(NROWT, 4), 256, 0, stream>>>(features, Wcat0, proj);
        k_gather<64,0><<<N_NODES/16, 256, 0, stream>>>(proj, tmp, rowptr, pidx, pnorm, h1);

        // layer 1: 64 -> 64, leaky
        k_selfgemm<64,64><<<NROWT, 256, 0, stream>>>(h1, loop1, bias1, tmp);
        k_projgemm<64,64><<<dim3(NROWT, 4), 256, 0, stream>>>(h1, Wcat1, proj);
        k_gather<64,0><<<N_NODES/16, 256, 0, stream>>>(proj, tmp, rowptr, pidx, pnorm, h2);

        // layer 2: 64 -> 32, sigmoid
        k_selfgemm<64,32><<<NROWT, 256, 0, stream>>>(h2, loop2, bias2, tmp);
        k_projgemm<64,32><<<dim3(NROWT, 2), 256, 0, stream>>>(h2, Wcat2, proj);
        k_gather<32,1><<<N_NODES/32, 256, 0, stream>>>(proj, tmp, rowptr, pidx, pnorm, logits);
    } else {
        // ================= fallback: round-2 atomic path =================
        size_t foff = branch_off;
        int* elist  = (int*)(ws + foff); foff += ELIST_CAP;
        int* hist_g = (int*)(ws + foff); foff += R_REL*NCHUNK;
        int* base_g = (int*)(ws + foff); foff += R_REL*NCHUNK;
        int* offs   = (int*)(ws + foff); foff += 16;

        hipMemsetAsync(elist, 0xFF, (size_t)ELIST_CAP*sizeof(int), stream);
        k_hist    <<<NCHUNK, 256, 0, stream>>>(etypes, hist_g);
        k_scan8   <<<1, NCHUNK, 0, stream>>>(hist_g, base_g, offs);
        k_scatter2<<<NCHUNK, 256, 0, stream>>>(etypes, base_g, elist);

        k_selfgemm<32,64><<<NROWT, 256, 0, stream>>>(features, loop0, bias0, h1);
        k_edgegemm<32,64><<<NTILES, 256, 0, stream>>>(features, Wcat0, src, dst, norm, elist, offs, h1);
        k_leaky<<<(N_NODES*64)/256, 256, 0, stream>>>(h1, N_NODES*64);

        k_selfgemm<64,64><<<NROWT, 256, 0, stream>>>(h1, loop1, bias1, h2);
        k_edgegemm<64,64><<<NTILES, 256, 0, stream>>>(h1, Wcat1, src, dst, norm, elist, offs, h2);
        k_leaky<<<(N_NODES*64)/256, 256, 0, stream>>>(h2, N_NODES*64);

        k_selfgemm<64,32><<<NROWT, 256, 0, stream>>>(h2, loop2, bias2, logits);
        k_edgegemm<64,32><<<NTILES, 256, 0, stream>>>(h2, Wcat2, src, dst, norm, elist, offs, logits);
        k_sigmoid<<<(N_NODES*32)/256, 256, 0, stream>>>(logits, N_NODES*32);
    }

    // decoder
    k_convt<<<(B_GR*IWID*IWID + 255)/256, 256, 0, stream>>>(logits, conv_w, conv_b, out);
}

// Round 4
// 646.103 us; speedup vs baseline: 3.4629x; 3.4629x over previous
//
#include <hip/hip_runtime.h>
#include <hip/hip_bf16.h>

// Problem constants (match reference)
#define B_GR   128
#define GWID   30
#define IWID   90
#define C_IN   32
#define R_REL  8
#define NBAS   4
#define N_NODES (B_GR*GWID*GWID)   // 115200
#define E_EDGES (N_NODES*8)        // 921600
#define NEG_SLOPE 0.01f

#define SCAN_BLOCKS (N_NODES/256)  // 450

// ======================================================================
// W_r = sum_b comp[r,b]*bases[b]  -> layout (R, din, dout), contiguous per r
// ======================================================================
__global__ void k_wcomp(const float* __restrict__ bases, const float* __restrict__ comp,
                        float* __restrict__ W, int din, int dout) {
    int idx = blockIdx.x*256 + threadIdx.x;
    int tot = R_REL*din*dout;
    if (idx >= tot) return;
    int r = idx/(din*dout), rem = idx%(din*dout);
    float acc = 0.f;
    #pragma unroll
    for (int b = 0; b < NBAS; ++b) acc += comp[r*NBAS + b]*bases[(size_t)b*din*dout + rem];
    W[idx] = acc;
}

// ======================================================================
// dst-CSR build (once per call; topology reused across all 3 layers)
// ======================================================================
__global__ void k_deg(const int* __restrict__ dst, int* __restrict__ deg) {
    int e = blockIdx.x*256 + threadIdx.x;
    if (e < E_EDGES) atomicAdd(&deg[dst[e]], 1);   // avg 8-way contention: cheap
}
__global__ __launch_bounds__(256) void k_scan1(const int* __restrict__ deg,
                                               int* __restrict__ rowptr,
                                               int* __restrict__ bsum) {
    __shared__ int s[256], s2[256];
    const int tid = threadIdx.x, gid = blockIdx.x*256 + tid;
    int v = deg[gid];
    s[tid] = v;
    __syncthreads();
    int* cur = s; int* nxt = s2;
    for (int d = 1; d < 256; d <<= 1) {
        int val = cur[tid];
        if (tid >= d) val += cur[tid - d];
        nxt[tid] = val;
        __syncthreads();
        int* t = cur; cur = nxt; nxt = t;
    }
    rowptr[gid] = cur[tid] - v;
    if (tid == 255) bsum[blockIdx.x] = cur[255];
}
__global__ __launch_bounds__(512) void k_scan2(int* __restrict__ bsum, int* __restrict__ rowptr) {
    __shared__ int s[512], s2[512];
    const int tid = threadIdx.x;
    int v = (tid < SCAN_BLOCKS) ? bsum[tid] : 0;
    s[tid] = v;
    __syncthreads();
    int* cur = s; int* nxt = s2;
    for (int d = 1; d < 512; d <<= 1) {
        int val = cur[tid];
        if (tid >= d) val += cur[tid - d];
        nxt[tid] = val;
        __syncthreads();
        int* t = cur; cur = nxt; nxt = t;
    }
    if (tid < SCAN_BLOCKS) bsum[tid] = cur[tid] - v;   // exclusive
    if (tid == 0) rowptr[N_NODES] = E_EDGES;
}
__global__ void k_scan3(int* __restrict__ rowptr, const int* __restrict__ bsum,
                        int* __restrict__ cursor) {
    int gid = blockIdx.x*256 + threadIdx.x;
    int v = rowptr[gid] + bsum[blockIdx.x];
    rowptr[gid] = v;
    cursor[gid] = v;
}
__global__ void k_scatter_dst(const int* __restrict__ dst, int* __restrict__ cursor,
                              int* __restrict__ eidx) {
    int e = blockIdx.x*256 + threadIdx.x;
    if (e < E_EDGES) {
        int pos = atomicAdd(&cursor[dst[e]], 1);
        eidx[pos] = e;
    }
}
// per-node counting sort of the CSR segment by etype:
// rowptr2[n*9+r] = start of relation-r run (rowptr2[n*9+8] = segment end)
// pidx2[slot] = src node, pnorm2[slot] = norm
__global__ void k_sortseg(const int* __restrict__ rowptr, const int* __restrict__ eidx,
                          const int* __restrict__ src, const int* __restrict__ et,
                          const float* __restrict__ norm,
                          int* __restrict__ rowptr2, int* __restrict__ pidx2,
                          float* __restrict__ pnorm2) {
    int n = blockIdx.x*256 + threadIdx.x;
    if (n >= N_NODES) return;
    int beg = rowptr[n], end = rowptr[n+1];
    int cnt[R_REL];
    #pragma unroll
    for (int r = 0; r < R_REL; ++r) cnt[r] = 0;
    for (int j = beg; j < end; ++j) cnt[et[eidx[j]]]++;
    int base[R_REL];
    int acc = beg;
    #pragma unroll
    for (int r = 0; r < R_REL; ++r) {
        base[r] = acc;
        rowptr2[n*9 + r] = acc;
        acc += cnt[r];
    }
    rowptr2[n*9 + 8] = acc;
    for (int j = beg; j < end; ++j) {
        int e = eidx[j];
        int r = et[e];
        int p = base[r]++;
        pidx2[p]  = src[e];
        pnorm2[p] = norm[e];
    }
}

// ======================================================================
// Fused RGCN layer (dst-major, atomic-free):
//   hout[n] = act( sum_{r=0..7} (sum_{e in in(n), et=r} norm*h[src]) @ W_r
//                  + h[n] @ loopw + bias )
// Block = 256 threads, owns 64 dst rows. 9 phases: r=0..7 gather+GEMM, r=8 self.
// ======================================================================
template<int DIN, int DOUT, int ACT>
__global__ __launch_bounds__(256) void k_fused(
        const float* __restrict__ h, const float* __restrict__ W,
        const float* __restrict__ loopw, const float* __restrict__ bias,
        const int* __restrict__ rowptr2, const int* __restrict__ pidx2,
        const float* __restrict__ pnorm2, float* __restrict__ hout) {
    __shared__ float As[64][DIN+4];     // +4 keeps 16B alignment per row
    __shared__ float Bs[DIN][DOUT];
    const int tid = threadIdx.x;
    const int node0 = blockIdx.x*64;

    // A-build mapping: 4 threads per node, each covers DIN/4 contiguous cols
    constexpr int TPN = 4;
    constexpr int CPT = DIN/TPN;        // 16 (DIN=64) or 8 (DIN=32)
    constexpr int F4  = CPT/4;          // 4 or 2 float4s
    const int ln = tid / TPN, cg = tid % TPN;
    const int node = node0 + ln;

    // GEMM mapping
    constexpr int TX = DOUT/4;          // 16 (DOUT=64) or 8 (DOUT=32)
    constexpr int TY = 256/TX;
    constexpr int RPT = 64/TY;          // 4 or 2
    const int tx = tid % TX, ty = tid / TX;
    float acc[RPT][4];
    #pragma unroll
    for (int i = 0; i < RPT; ++i) { acc[i][0]=acc[i][1]=acc[i][2]=acc[i][3]=0.f; }

    for (int r = 0; r <= R_REL; ++r) {
        __syncthreads();   // protect As/Bs reuse against previous GEMM reads

        // stage B (16 KB max, coalesced float4)
        const float* Bsrc = (r < R_REL) ? (W + (size_t)r*DIN*DOUT) : loopw;
        constexpr int BW4 = DIN*DOUT/4;
        for (int idx = tid; idx < BW4; idx += 256)
            reinterpret_cast<float4*>(Bs)[idx] =
                reinterpret_cast<const float4*>(Bsrc)[idx];

        // build A row slice
        float4 a[F4];
        if (r < R_REL) {
            #pragma unroll
            for (int f = 0; f < F4; ++f) a[f] = make_float4(0.f,0.f,0.f,0.f);
            const int b2 = rowptr2[node*9 + r];
            const int e2 = rowptr2[node*9 + r + 1];
            for (int j = b2; j < e2; ++j) {
                int p = pidx2[j];
                float nm = pnorm2[j];
                const float4* hp = reinterpret_cast<const float4*>(&h[(size_t)p*DIN + cg*CPT]);
                #pragma unroll
                for (int f = 0; f < F4; ++f) {
                    float4 v = hp[f];
                    a[f].x += nm*v.x; a[f].y += nm*v.y;
                    a[f].z += nm*v.z; a[f].w += nm*v.w;
                }
            }
        } else {
            const float4* hp = reinterpret_cast<const float4*>(&h[(size_t)node*DIN + cg*CPT]);
            #pragma unroll
            for (int f = 0; f < F4; ++f) a[f] = hp[f];
        }
        #pragma unroll
        for (int f = 0; f < F4; ++f)
            *reinterpret_cast<float4*>(&As[ln][cg*CPT + f*4]) = a[f];
        __syncthreads();

        // C += A @ B
        #pragma unroll 8
        for (int k = 0; k < DIN; ++k) {
            float4 bv = *reinterpret_cast<const float4*>(&Bs[k][tx*4]);
            #pragma unroll
            for (int i = 0; i < RPT; ++i) {
                float av = As[ty*RPT + i][k];
                acc[i][0] += av*bv.x; acc[i][1] += av*bv.y;
                acc[i][2] += av*bv.z; acc[i][3] += av*bv.w;
            }
        }
    }

    // epilogue: bias + activation + store
    float b0 = bias[tx*4+0], b1 = bias[tx*4+1], b2 = bias[tx*4+2], b3 = bias[tx*4+3];
    #pragma unroll
    for (int i = 0; i < RPT; ++i) {
        float4 o;
        o.x = acc[i][0] + b0; o.y = acc[i][1] + b1;
        o.z = acc[i][2] + b2; o.w = acc[i][3] + b3;
        if (ACT == 0) {
            o.x = (o.x >= 0.f) ? o.x : NEG_SLOPE*o.x;
            o.y = (o.y >= 0.f) ? o.y : NEG_SLOPE*o.y;
            o.z = (o.z >= 0.f) ? o.z : NEG_SLOPE*o.z;
            o.w = (o.w >= 0.f) ? o.w : NEG_SLOPE*o.w;
        } else {
            o.x = 1.f/(1.f + __expf(-o.x));
            o.y = 1.f/(1.f + __expf(-o.y));
            o.z = 1.f/(1.f + __expf(-o.z));
            o.w = 1.f/(1.f + __expf(-o.w));
        }
        *reinterpret_cast<float4*>(&hout[(size_t)(node0 + ty*RPT + i)*DOUT + tx*4]) = o;
    }
}

// ======================================================================
// conv-transpose decoder + sigmoid
// ======================================================================
__global__ __launch_bounds__(256) void k_convt(const float* __restrict__ logits,
        const float* __restrict__ w, const float* __restrict__ cb, float* __restrict__ out) {
    __shared__ float s_w[49*32];
    const int tid = threadIdx.x;
    for (int idx = tid; idx < 49*32; idx += 256) {
        int tap = idx/32, c = idx%32;
        s_w[tap*32 + c] = w[c*49 + tap];
    }
    __syncthreads();
    int g = blockIdx.x*256 + tid;
    if (g >= B_GR*IWID*IWID) return;
    int b = g/(IWID*IWID);
    int rem = g%(IWID*IWID);
    int oy = rem/IWID, ox = rem%IWID;

    float acc = cb[0];
    for (int ky = 0; ky < 7; ++ky) {
        int t = oy + 2 - ky;
        if (t < 0 || (t % 3) != 0) continue;
        int iy = t/3; if (iy >= GWID) continue;
        for (int kx = 0; kx < 7; ++kx) {
            int u = ox + 2 - kx;
            if (u < 0 || (u % 3) != 0) continue;
            int ix = u/3; if (ix >= GWID) continue;
            const float4* xp = reinterpret_cast<const float4*>(&logits[(((size_t)b*GWID + iy)*GWID + ix)*32]);
            const float4* wp = reinterpret_cast<const float4*>(&s_w[(ky*7 + kx)*32]);
            #pragma unroll
            for (int c4 = 0; c4 < 8; ++c4) {
                float4 xv = xp[c4], wv = wp[c4];
                acc += xv.x*wv.x + xv.y*wv.y + xv.z*wv.z + xv.w*wv.w;
            }
        }
    }
    out[g] = 1.f/(1.f + __expf(-acc));
}

// ======================================================================
// host
// ======================================================================
extern "C" void kernel_launch(void* const* d_in, const int* in_sizes, int n_in,
                              void* d_out, int out_size, void* d_ws, size_t ws_size,
                              hipStream_t stream) {
    const float* features = (const float*)d_in[0];
    const int*   src      = (const int*)  d_in[1];
    const int*   dst      = (const int*)  d_in[2];
    const int*   etypes   = (const int*)  d_in[3];
    const float* norm     = (const float*)d_in[4];
    const float* bases0 = (const float*)d_in[5];
    const float* comp0  = (const float*)d_in[6];
    const float* loop0  = (const float*)d_in[7];
    const float* bias0  = (const float*)d_in[8];
    const float* bases1 = (const float*)d_in[9];
    const float* comp1  = (const float*)d_in[10];
    const float* loop1  = (const float*)d_in[11];
    const float* bias1  = (const float*)d_in[12];
    const float* bases2 = (const float*)d_in[13];
    const float* comp2  = (const float*)d_in[14];
    const float* loop2  = (const float*)d_in[15];
    const float* bias2  = (const float*)d_in[16];
    const float* conv_w = (const float*)d_in[17];
    const float* conv_b = (const float*)d_in[18];
    float* out = (float*)d_out;

    // ---- workspace carve-up (float units), total ~75 MB ----
    float* ws = (float*)d_ws;
    size_t off = 0;
    float* W0 = ws + off; off += (size_t)R_REL*32*64;   // 16384
    float* W1 = ws + off; off += (size_t)R_REL*64*64;   // 32768
    float* W2 = ws + off; off += (size_t)R_REL*64*32;   // 16384
    float* h1 = ws + off; off += (size_t)N_NODES*64;    // 29.5 MB (logits aliases this)
    float* h2 = ws + off; off += (size_t)N_NODES*64;    // 29.5 MB
    int*   rowptr  = (int*)(ws + off); off += (size_t)N_NODES + 16;
    int*   rowptr2 = (int*)(ws + off); off += (size_t)N_NODES*9 + 16;
    int*   deg     = (int*)(ws + off); off += (size_t)N_NODES;   // also cursor
    int*   eidx    = (int*)(ws + off); off += (size_t)E_EDGES;
    int*   pidx2   = (int*)(ws + off); off += (size_t)E_EDGES;
    float* pnorm2  = ws + off; off += (size_t)E_EDGES;
    int*   bsum    = (int*)(ws + off); off += 512;
    float* logits  = h1;   // layer-2 reads h2, writes here: no conflict

    const int ebl = (E_EDGES + 255)/256;

    // ---- weight prep ----
    k_wcomp<<<(R_REL*32*64 + 255)/256, 256, 0, stream>>>(bases0, comp0, W0, 32, 64);
    k_wcomp<<<(R_REL*64*64 + 255)/256, 256, 0, stream>>>(bases1, comp1, W1, 64, 64);
    k_wcomp<<<(R_REL*64*32 + 255)/256, 256, 0, stream>>>(bases2, comp2, W2, 64, 32);

    // ---- dst-CSR + per-node etype sort (reused by all 3 layers) ----
    hipMemsetAsync(deg, 0, (size_t)N_NODES*sizeof(int), stream);
    k_deg        <<<ebl, 256, 0, stream>>>(dst, deg);
    k_scan1      <<<SCAN_BLOCKS, 256, 0, stream>>>(deg, rowptr, bsum);
    k_scan2      <<<1, 512, 0, stream>>>(bsum, rowptr);
    k_scan3      <<<SCAN_BLOCKS, 256, 0, stream>>>(rowptr, bsum, deg);  // deg -> cursor
    k_scatter_dst<<<ebl, 256, 0, stream>>>(dst, deg, eidx);
    k_sortseg    <<<SCAN_BLOCKS, 256, 0, stream>>>(rowptr, eidx, src, etypes, norm,
                                                   rowptr2, pidx2, pnorm2);

    const int NROWT = N_NODES/64;   // 1800

    // ---- 3 fused layers ----
    k_fused<32,64,0><<<NROWT, 256, 0, stream>>>(features, W0, loop0, bias0,
                                                rowptr2, pidx2, pnorm2, h1);
    k_fused<64,64,0><<<NROWT, 256, 0, stream>>>(h1, W1, loop1, bias1,
                                                rowptr2, pidx2, pnorm2, h2);
    k_fused<64,32,1><<<NROWT, 256, 0, stream>>>(h2, W2, loop2, bias2,
                                                rowptr2, pidx2, pnorm2, logits);

    // ---- decoder ----
    k_convt<<<(B_GR*IWID*IWID + 255)/256, 256, 0, stream>>>(logits, conv_w, conv_b, out);
}

// Round 5
// 439.474 us; speedup vs baseline: 5.0910x; 1.4702x over previous
//
#include <hip/hip_runtime.h>
#include <hip/hip_bf16.h>

// Problem constants (match reference)
#define B_GR   128
#define GWID   30
#define IWID   90
#define C_IN   32
#define R_REL  8
#define NBAS   4
#define N_NODES (B_GR*GWID*GWID)   // 115200
#define E_EDGES (N_NODES*8)        // 921600
#define NEG_SLOPE 0.01f

#define SCAN_BLOCKS (N_NODES/256)  // 450

typedef __attribute__((ext_vector_type(8))) __bf16 bf16x8;
typedef __attribute__((ext_vector_type(4))) float f32x4;

// ======================================================================
// Weight prep: Wt[r][c][k] = bf16( sum_b comp[r,b]*bases[b,k,c] )   (B^T layout)
//              loopt[c][k] = bf16( loopw[k,c] )
// ======================================================================
__global__ void k_wcomp_t(const float* __restrict__ bases, const float* __restrict__ comp,
                          __bf16* __restrict__ Wt, int din, int dout) {
    int idx = blockIdx.x*256 + threadIdx.x;
    int tot = R_REL*din*dout;
    if (idx >= tot) return;
    int r = idx/(dout*din), rem = idx%(dout*din);
    int c = rem/din, k = rem%din;
    float acc = 0.f;
    #pragma unroll
    for (int b = 0; b < NBAS; ++b)
        acc += comp[r*NBAS + b]*bases[((size_t)b*din + k)*dout + c];
    Wt[idx] = (__bf16)acc;
}
__global__ void k_loop_t(const float* __restrict__ loopw, __bf16* __restrict__ loopt,
                         int din, int dout) {
    int idx = blockIdx.x*256 + threadIdx.x;
    if (idx >= din*dout) return;
    int c = idx/din, k = idx%din;
    loopt[idx] = (__bf16)loopw[(size_t)k*dout + c];
}

// ======================================================================
// prep: (dst,etype)-binned CSR, no intermediate edge list
// ======================================================================
__global__ void k_deg2(const int* __restrict__ dst, const int* __restrict__ et,
                       int* __restrict__ deg2) {
    int e = blockIdx.x*256 + threadIdx.x;
    if (e < E_EDGES) atomicAdd(&deg2[dst[e]*R_REL + et[e]], 1);
}
__global__ void k_degsum(const int* __restrict__ deg2, int* __restrict__ deg) {
    int n = blockIdx.x*256 + threadIdx.x;
    if (n >= N_NODES) return;
    int s = 0;
    #pragma unroll
    for (int r = 0; r < R_REL; ++r) s += deg2[n*R_REL + r];
    deg[n] = s;
}
__global__ __launch_bounds__(256) void k_scan1(const int* __restrict__ deg,
                                               int* __restrict__ rowptr,
                                               int* __restrict__ bsum) {
    __shared__ int s[256], s2[256];
    const int tid = threadIdx.x, gid = blockIdx.x*256 + tid;
    int v = deg[gid];
    s[tid] = v;
    __syncthreads();
    int* cur = s; int* nxt = s2;
    for (int d = 1; d < 256; d <<= 1) {
        int val = cur[tid];
        if (tid >= d) val += cur[tid - d];
        nxt[tid] = val;
        __syncthreads();
        int* t = cur; cur = nxt; nxt = t;
    }
    rowptr[gid] = cur[tid] - v;
    if (tid == 255) bsum[blockIdx.x] = cur[255];
}
__global__ __launch_bounds__(512) void k_scan2(int* __restrict__ bsum, int* __restrict__ rowptr) {
    __shared__ int s[512], s2[512];
    const int tid = threadIdx.x;
    int v = (tid < SCAN_BLOCKS) ? bsum[tid] : 0;
    s[tid] = v;
    __syncthreads();
    int* cur = s; int* nxt = s2;
    for (int d = 1; d < 512; d <<= 1) {
        int val = cur[tid];
        if (tid >= d) val += cur[tid - d];
        nxt[tid] = val;
        __syncthreads();
        int* t = cur; cur = nxt; nxt = t;
    }
    if (tid < SCAN_BLOCKS) bsum[tid] = cur[tid] - v;   // exclusive
    if (tid == 0) rowptr[N_NODES] = E_EDGES;
}
__global__ void k_scan3(int* __restrict__ rowptr, const int* __restrict__ bsum) {
    int gid = blockIdx.x*256 + threadIdx.x;
    rowptr[gid] = rowptr[gid] + bsum[blockIdx.x];
}
__global__ void k_rowptr2(const int* __restrict__ rowptr, const int* __restrict__ deg2,
                          int* __restrict__ rowptr2, int* __restrict__ cursor2) {
    int n = blockIdx.x*256 + threadIdx.x;
    if (n >= N_NODES) return;
    int base = rowptr[n];
    #pragma unroll
    for (int r = 0; r < R_REL; ++r) {
        rowptr2[n*9 + r] = base;
        cursor2[n*R_REL + r] = base;
        base += deg2[n*R_REL + r];
    }
    rowptr2[n*9 + 8] = base;
}
__global__ void k_scatter_direct(const int* __restrict__ src, const int* __restrict__ dst,
                                 const int* __restrict__ et, const float* __restrict__ norm,
                                 int* __restrict__ cursor2, int* __restrict__ pidx2,
                                 float* __restrict__ pnorm2) {
    int e = blockIdx.x*256 + threadIdx.x;
    if (e < E_EDGES) {
        int pos = atomicAdd(&cursor2[dst[e]*R_REL + et[e]], 1);
        pidx2[pos]  = src[e];
        pnorm2[pos] = norm[e];
    }
}

// ======================================================================
// Fused RGCN layer with MFMA (per-wave, no LDS, no barriers):
//   hout[n] = act( sum_r (sum_{e in in(n),et=r} norm*h[src]) @ W_r + h[n]@loopw + bias )
// Wave owns 16 dst rows. Lane l: m = l&15 (row), g = l>>4 (K-group).
// A-frag: lane holds cols ks*32 + g*8 .. +7 of its row (gather-summed in f32).
// B-frag: Wt[r] is [DOUT][DIN] bf16 (B^T): lane reads Wt[nf*16+m][ks*32+g*8..+7].
// D: row = g*4+reg, col = nf*16+m  (m89-verified C/D layout).
// ======================================================================
template<int DIN, int DOUT, int ACT, int IN_F32>
__global__ __launch_bounds__(256) void k_fused_mfma(
        const void* __restrict__ hin, const __bf16* __restrict__ Wt,
        const __bf16* __restrict__ loopt, const float* __restrict__ bias,
        const int* __restrict__ rowptr2, const int* __restrict__ pidx2,
        const float* __restrict__ pnorm2, __bf16* __restrict__ hout) {
    constexpr int KS = DIN/32;
    constexpr int NF = DOUT/16;
    const int tid = threadIdx.x;
    const int w = tid >> 6;
    const int l = tid & 63;
    const int m = l & 15, g = l >> 4;
    const int node0 = blockIdx.x*64 + w*16;
    const int node = node0 + m;

    f32x4 acc[NF];
    #pragma unroll
    for (int nf = 0; nf < NF; ++nf) acc[nf] = (f32x4){0.f,0.f,0.f,0.f};

    for (int r = 0; r < 9; ++r) {
        // ---- build A fragment: f32 gather-sum of this lane's K-slice ----
        float ka[KS][8];
        #pragma unroll
        for (int ks = 0; ks < KS; ++ks)
            #pragma unroll
            for (int j = 0; j < 8; ++j) ka[ks][j] = 0.f;

        if (r < R_REL) {
            const int jb = rowptr2[node*9 + r];
            const int je = rowptr2[node*9 + r + 1];
            for (int j = jb; j < je; ++j) {
                const int p = pidx2[j];
                const float nm = pnorm2[j];
                if (IN_F32) {
                    const float* hp = (const float*)hin + (size_t)p*DIN + g*8;
                    #pragma unroll
                    for (int ks = 0; ks < KS; ++ks) {
                        float4 v0 = *(const float4*)(hp + ks*32);
                        float4 v1 = *(const float4*)(hp + ks*32 + 4);
                        ka[ks][0] += nm*v0.x; ka[ks][1] += nm*v0.y;
                        ka[ks][2] += nm*v0.z; ka[ks][3] += nm*v0.w;
                        ka[ks][4] += nm*v1.x; ka[ks][5] += nm*v1.y;
                        ka[ks][6] += nm*v1.z; ka[ks][7] += nm*v1.w;
                    }
                } else {
                    const __bf16* hp = (const __bf16*)hin + (size_t)p*DIN + g*8;
                    #pragma unroll
                    for (int ks = 0; ks < KS; ++ks) {
                        bf16x8 v = *(const bf16x8*)(hp + ks*32);
                        #pragma unroll
                        for (int jj = 0; jj < 8; ++jj) ka[ks][jj] += nm*(float)v[jj];
                    }
                }
            }
        } else {
            // self-loop: A row = h[node]
            if (IN_F32) {
                const float* hp = (const float*)hin + (size_t)node*DIN + g*8;
                #pragma unroll
                for (int ks = 0; ks < KS; ++ks) {
                    float4 v0 = *(const float4*)(hp + ks*32);
                    float4 v1 = *(const float4*)(hp + ks*32 + 4);
                    ka[ks][0] = v0.x; ka[ks][1] = v0.y; ka[ks][2] = v0.z; ka[ks][3] = v0.w;
                    ka[ks][4] = v1.x; ka[ks][5] = v1.y; ka[ks][6] = v1.z; ka[ks][7] = v1.w;
                }
            } else {
                const __bf16* hp = (const __bf16*)hin + (size_t)node*DIN + g*8;
                #pragma unroll
                for (int ks = 0; ks < KS; ++ks) {
                    bf16x8 v = *(const bf16x8*)(hp + ks*32);
                    #pragma unroll
                    for (int jj = 0; jj < 8; ++jj) ka[ks][jj] = (float)v[jj];
                }
            }
        }

        // pack bf16 A fragments
        bf16x8 fa[KS];
        #pragma unroll
        for (int ks = 0; ks < KS; ++ks)
            #pragma unroll
            for (int jj = 0; jj < 8; ++jj) fa[ks][jj] = (__bf16)ka[ks][jj];

        // B fragments from global (L1-hot: same 8-16 KB reused by all blocks)
        const __bf16* Bt = (r < R_REL) ? (Wt + (size_t)r*DOUT*DIN) : loopt;
        #pragma unroll
        for (int ks = 0; ks < KS; ++ks) {
            #pragma unroll
            for (int nf = 0; nf < NF; ++nf) {
                bf16x8 fb = *(const bf16x8*)(Bt + (size_t)(nf*16 + m)*DIN + ks*32 + g*8);
                acc[nf] = __builtin_amdgcn_mfma_f32_16x16x32_bf16(fa[ks], fb, acc[nf], 0, 0, 0);
            }
        }
    }

    // ---- epilogue: bias + activation + bf16 store ----
    #pragma unroll
    for (int nf = 0; nf < NF; ++nf) {
        const int col = nf*16 + m;
        const float bv = bias[col];
        #pragma unroll
        for (int ri = 0; ri < 4; ++ri) {
            const int orow = node0 + g*4 + ri;
            float v = acc[nf][ri] + bv;
            if (ACT == 0) v = (v >= 0.f) ? v : NEG_SLOPE*v;
            else          v = 1.f/(1.f + __expf(-v));
            hout[(size_t)orow*DOUT + col] = (__bf16)v;
        }
    }
}

// ======================================================================
// conv-transpose decoder + sigmoid (bf16 logits input)
// ======================================================================
__global__ __launch_bounds__(256) void k_convt(const __bf16* __restrict__ logits,
        const float* __restrict__ w, const float* __restrict__ cb, float* __restrict__ out) {
    __shared__ float s_w[49*32];
    const int tid = threadIdx.x;
    for (int idx = tid; idx < 49*32; idx += 256) {
        int tap = idx/32, c = idx%32;
        s_w[tap*32 + c] = w[c*49 + tap];
    }
    __syncthreads();
    int gidx = blockIdx.x*256 + tid;
    if (gidx >= B_GR*IWID*IWID) return;
    int b = gidx/(IWID*IWID);
    int rem = gidx%(IWID*IWID);
    int oy = rem/IWID, ox = rem%IWID;

    float acc = cb[0];
    for (int ky = 0; ky < 7; ++ky) {
        int t = oy + 2 - ky;
        if (t < 0 || (t % 3) != 0) continue;
        int iy = t/3; if (iy >= GWID) continue;
        for (int kx = 0; kx < 7; ++kx) {
            int u = ox + 2 - kx;
            if (u < 0 || (u % 3) != 0) continue;
            int ix = u/3; if (ix >= GWID) continue;
            const bf16x8* xp = (const bf16x8*)&logits[(((size_t)b*GWID + iy)*GWID + ix)*32];
            const float* wp = &s_w[(ky*7 + kx)*32];
            #pragma unroll
            for (int c8 = 0; c8 < 4; ++c8) {
                bf16x8 xv = xp[c8];
                #pragma unroll
                for (int jj = 0; jj < 8; ++jj)
                    acc += (float)xv[jj]*wp[c8*8 + jj];
            }
        }
    }
    out[gidx] = 1.f/(1.f + __expf(-acc));
}

// ======================================================================
// host
// ======================================================================
extern "C" void kernel_launch(void* const* d_in, const int* in_sizes, int n_in,
                              void* d_out, int out_size, void* d_ws, size_t ws_size,
                              hipStream_t stream) {
    const float* features = (const float*)d_in[0];
    const int*   src      = (const int*)  d_in[1];
    const int*   dst      = (const int*)  d_in[2];
    const int*   etypes   = (const int*)  d_in[3];
    const float* norm     = (const float*)d_in[4];
    const float* bases0 = (const float*)d_in[5];
    const float* comp0  = (const float*)d_in[6];
    const float* loop0  = (const float*)d_in[7];
    const float* bias0  = (const float*)d_in[8];
    const float* bases1 = (const float*)d_in[9];
    const float* comp1  = (const float*)d_in[10];
    const float* loop1  = (const float*)d_in[11];
    const float* bias1  = (const float*)d_in[12];
    const float* bases2 = (const float*)d_in[13];
    const float* comp2  = (const float*)d_in[14];
    const float* loop2  = (const float*)d_in[15];
    const float* bias2  = (const float*)d_in[16];
    const float* conv_w = (const float*)d_in[17];
    const float* conv_b = (const float*)d_in[18];
    float* out = (float*)d_out;

    // ---- workspace carve-up (float units, each chunk 16B-aligned) ----
    float* ws = (float*)d_ws;
    size_t off = 0;
    __bf16* Wt0   = (__bf16*)(ws + off); off += (size_t)R_REL*64*32/2;   // 8192
    __bf16* Wt1   = (__bf16*)(ws + off); off += (size_t)R_REL*64*64/2;   // 16384
    __bf16* Wt2   = (__bf16*)(ws + off); off += (size_t)R_REL*32*64/2;   // 8192
    __bf16* lt0   = (__bf16*)(ws + off); off += (size_t)64*32/2;
    __bf16* lt1   = (__bf16*)(ws + off); off += (size_t)64*64/2;
    __bf16* lt2   = (__bf16*)(ws + off); off += (size_t)32*64/2;
    __bf16* h1    = (__bf16*)(ws + off); off += (size_t)N_NODES*64/2;
    __bf16* h2    = (__bf16*)(ws + off); off += (size_t)N_NODES*64/2;
    __bf16* lg    = (__bf16*)(ws + off); off += (size_t)N_NODES*32/2;
    int* rowptr   = (int*)(ws + off); off += (size_t)N_NODES + 4;
    int* rowptr2  = (int*)(ws + off); off += (size_t)N_NODES*9 + 16;
    int* deg2     = (int*)(ws + off); off += (size_t)N_NODES*R_REL;
    int* cursor2  = (int*)(ws + off); off += (size_t)N_NODES*R_REL;
    int* deg      = (int*)(ws + off); off += (size_t)N_NODES;
    int* bsum     = (int*)(ws + off); off += 512;
    int* pidx2    = (int*)(ws + off); off += (size_t)E_EDGES;
    float* pnorm2 = ws + off; off += (size_t)E_EDGES;

    const int ebl = (E_EDGES + 255)/256;

    // ---- weight prep (transposed bf16) ----
    k_wcomp_t<<<(R_REL*32*64 + 255)/256, 256, 0, stream>>>(bases0, comp0, Wt0, 32, 64);
    k_wcomp_t<<<(R_REL*64*64 + 255)/256, 256, 0, stream>>>(bases1, comp1, Wt1, 64, 64);
    k_wcomp_t<<<(R_REL*64*32 + 255)/256, 256, 0, stream>>>(bases2, comp2, Wt2, 64, 32);
    k_loop_t<<<(32*64 + 255)/256, 256, 0, stream>>>(loop0, lt0, 32, 64);
    k_loop_t<<<(64*64 + 255)/256, 256, 0, stream>>>(loop1, lt1, 64, 64);
    k_loop_t<<<(64*32 + 255)/256, 256, 0, stream>>>(loop2, lt2, 64, 32);

    // ---- (dst,etype)-binned CSR (reused by all 3 layers) ----
    hipMemsetAsync(deg2, 0, (size_t)N_NODES*R_REL*sizeof(int), stream);
    k_deg2   <<<ebl, 256, 0, stream>>>(dst, etypes, deg2);
    k_degsum <<<SCAN_BLOCKS, 256, 0, stream>>>(deg2, deg);
    k_scan1  <<<SCAN_BLOCKS, 256, 0, stream>>>(deg, rowptr, bsum);
    k_scan2  <<<1, 512, 0, stream>>>(bsum, rowptr);
    k_scan3  <<<SCAN_BLOCKS, 256, 0, stream>>>(rowptr, bsum);
    k_rowptr2<<<SCAN_BLOCKS, 256, 0, stream>>>(rowptr, deg2, rowptr2, cursor2);
    k_scatter_direct<<<ebl, 256, 0, stream>>>(src, dst, etypes, norm, cursor2, pidx2, pnorm2);

    const int NROWT = N_NODES/64;   // 1800

    // ---- 3 fused MFMA layers ----
    k_fused_mfma<32,64,0,1><<<NROWT, 256, 0, stream>>>(features, Wt0, lt0, bias0,
                                                       rowptr2, pidx2, pnorm2, h1);
    k_fused_mfma<64,64,0,0><<<NROWT, 256, 0, stream>>>(h1, Wt1, lt1, bias1,
                                                       rowptr2, pidx2, pnorm2, h2);
    k_fused_mfma<64,32,1,0><<<NROWT, 256, 0, stream>>>(h2, Wt2, lt2, bias2,
                                                       rowptr2, pidx2, pnorm2, lg);

    // ---- decoder ----
    k_convt<<<(B_GR*IWID*IWID + 255)/256, 256, 0, stream>>>(lg, conv_w, conv_b, out);
}